// Round 2
// baseline (226.683 us; speedup 1.0000x reference)
//
#include <hip/hip_runtime.h>
#include <hip/hip_bf16.h>

// Problem constants: N=50000, K=32, D=128.
#define D     128
#define TWO_D 256
#define KNB   32

typedef __attribute__((ext_vector_type(8))) short    s8;   // 8 x 16-bit (4 VGPR)
typedef __attribute__((ext_vector_type(8))) _Float16 h8;   // mfma operand view
typedef __attribute__((ext_vector_type(2))) _Float16 h2v;
typedef __attribute__((ext_vector_type(4))) float    f4;   // MFMA acc

__device__ inline unsigned short f2h(float f) {
    return __builtin_bit_cast(unsigned short, (_Float16)f);
}
__device__ inline float h2f(unsigned short u) {
    return (float)__builtin_bit_cast(_Float16, u);
}

union v16u { s8 s; h2v h[4]; };

// 8-elem fp16 dot with f32 accumulate; v_dot2_f32_f16 when available.
__device__ inline float dot8(s8 x, s8 w, float acc) {
#if __has_builtin(__builtin_amdgcn_fdot2)
    v16u ux, uw; ux.s = x; uw.s = w;
#pragma unroll
    for (int j = 0; j < 4; ++j)
        acc = __builtin_amdgcn_fdot2(ux.h[j], uw.h[j], acc, false);
#else
#pragma unroll
    for (int j = 0; j < 8; ++j)
        acc = fmaf(h2f((unsigned short)x[j]), h2f((unsigned short)w[j]), acc);
#endif
    return acc;
}

// ---------------------------------------------------------------------------
// Cast kernel: v_fea, t_emb (f32) -> packed ph[n][0:128]=v, [128:256]=t (fp16).
// One contiguous 512B row per node => each edge gather is a single 512B block.
// ---------------------------------------------------------------------------
__global__ __launch_bounds__(256) void cast_kernel(
    const float* __restrict__ a, const float* __restrict__ b,
    unsigned short* __restrict__ ph, int total)   // total = M*16
{
    int i = blockIdx.x * 256 + threadIdx.x;
    if (i >= total) return;
    int n = i >> 4, j = i & 15;
    const float4* pv = (const float4*)(a + (size_t)n * D + j * 8);
    const float4* pt = (const float4*)(b + (size_t)n * D + j * 8);
    float4 v0 = pv[0], v1 = pv[1];
    float4 t0 = pt[0], t1 = pt[1];
    s8 qv, qt;
    qv[0]=(short)f2h(v0.x); qv[1]=(short)f2h(v0.y); qv[2]=(short)f2h(v0.z); qv[3]=(short)f2h(v0.w);
    qv[4]=(short)f2h(v1.x); qv[5]=(short)f2h(v1.y); qv[6]=(short)f2h(v1.z); qv[7]=(short)f2h(v1.w);
    qt[0]=(short)f2h(t0.x); qt[1]=(short)f2h(t0.y); qt[2]=(short)f2h(t0.z); qt[3]=(short)f2h(t0.w);
    qt[4]=(short)f2h(t1.x); qt[5]=(short)f2h(t1.y); qt[6]=(short)f2h(t1.z); qt[7]=(short)f2h(t1.w);
    *(s8*)(ph + (size_t)n * TWO_D + j * 8)     = qv;
    *(s8*)(ph + (size_t)n * TWO_D + D + j * 8) = qt;
}

// ---------------------------------------------------------------------------
// Kernel A: wq = ph @ W^T via fp16 MFMA. A-tiles read pre-cast packed fp16
// rows directly; only W (L2-resident) converted inline. wq stored fp16.
// 128x128 tile, BK=32, 4 waves; wave w: rows [w*32, w*32+32).
// ---------------------------------------------------------------------------
#define BM 128
#define BN 128
#define BK 32
#define LDT 56   // row stride (elems): 112 B = 16B-aligned; 2-way banks only

__global__ __launch_bounds__(256) void gemm_wq_mfma(
    const unsigned short* __restrict__ ph,
    const float* __restrict__ W, unsigned short* __restrict__ wq_h, int M)
{
    __shared__ unsigned short As[BM][LDT];
    __shared__ unsigned short Bs[BN][LDT];

    const int tid  = threadIdx.x;
    const int w    = tid >> 6;
    const int lane = tid & 63;
    const int quad = lane >> 4;
    const int l16  = lane & 15;
    const int row0 = blockIdx.x * BM;
    const int i0   = blockIdx.y * BN;

    f4 acc[2][8] = {};

    const int srow = tid >> 1;          // 0..127 (tile row this thread stages)
    const int seg  = tid & 1;           // 16-elem k-segment
    int ga = row0 + srow; if (ga >= M) ga = M - 1;   // clamp (stores guarded)

    for (int kt = 0; kt < TWO_D; kt += BK) {
        // A: packed fp16 source, direct copy. 32 B/thread.
        const unsigned short* pa = ph + (size_t)ga * TWO_D + kt + seg * 16;
        s8 a0 = *(const s8*)(pa);
        s8 a1 = *(const s8*)(pa + 8);
        // B: W f32 rows, inline cvt. 16 floats/thread.
        const float* pb = W + (size_t)(i0 + srow) * TWO_D + kt + seg * 16;
        float4 b0 = *(const float4*)(pb);
        float4 b1 = *(const float4*)(pb + 4);
        float4 b2 = *(const float4*)(pb + 8);
        float4 b3 = *(const float4*)(pb + 12);

        __syncthreads();   // prior iter's frag reads done before overwrite
        *(s8*)&As[srow][seg * 16]     = a0;
        *(s8*)&As[srow][seg * 16 + 8] = a1;
        {
            s8 q0, q1;
            q0[0]=(short)f2h(b0.x); q0[1]=(short)f2h(b0.y); q0[2]=(short)f2h(b0.z); q0[3]=(short)f2h(b0.w);
            q0[4]=(short)f2h(b1.x); q0[5]=(short)f2h(b1.y); q0[6]=(short)f2h(b1.z); q0[7]=(short)f2h(b1.w);
            q1[0]=(short)f2h(b2.x); q1[1]=(short)f2h(b2.y); q1[2]=(short)f2h(b2.z); q1[3]=(short)f2h(b2.w);
            q1[4]=(short)f2h(b3.x); q1[5]=(short)f2h(b3.y); q1[6]=(short)f2h(b3.z); q1[7]=(short)f2h(b3.w);
            *(s8*)&Bs[srow][seg * 16]     = q0;
            *(s8*)&Bs[srow][seg * 16 + 8] = q1;
        }
        __syncthreads();

        // A frag: m = lane&15 (+tile), k = quad*8+j; B frag: n = lane&15 (+tile).
        s8 af0 = *(const s8*)&As[w * 32 + l16][quad * 8];
        s8 af1 = *(const s8*)&As[w * 32 + 16 + l16][quad * 8];
#pragma unroll
        for (int nt = 0; nt < 8; ++nt) {
            s8 bf = *(const s8*)&Bs[nt * 16 + l16][quad * 8];
            acc[0][nt] = __builtin_amdgcn_mfma_f32_16x16x32_f16(
                __builtin_bit_cast(h8, af0), __builtin_bit_cast(h8, bf), acc[0][nt], 0, 0, 0);
            acc[1][nt] = __builtin_amdgcn_mfma_f32_16x16x32_f16(
                __builtin_bit_cast(h8, af1), __builtin_bit_cast(h8, bf), acc[1][nt], 0, 0, 0);
        }
    }

    // Epilogue: D layout col=lane&15, row=quad*4+r.
#pragma unroll
    for (int mt = 0; mt < 2; ++mt) {
#pragma unroll
        for (int nt = 0; nt < 8; ++nt) {
#pragma unroll
            for (int r = 0; r < 4; ++r) {
                int grow = row0 + w * 32 + mt * 16 + quad * 4 + r;
                if (grow < M)
                    wq_h[(size_t)grow * TWO_D + i0 + nt * 16 + l16] = f2h(acc[mt][nt][r]);
            }
        }
    }
}

// ---------------------------------------------------------------------------
// Kernel B: gather + score + softmax + weighted sum. One wave per row, 4
// rows/block, NO LDS. Phased for ILP (not per-pass serial chains):
//   Phase 1: ALL 16 gather loads issued, pinned by sched_barrier(0).
//            Data must stay live until phase 4 => compiler cannot sink them.
//   Phase 2: 8 independent partial-dot chains.
//   Phase 3: 8 independent 16-lane shuffle trees + group-max exchange;
//            global max known before any exp => exact softmax, 8 exps/lane
//            (was 32), no rescale branch.
//   Phase 4: weighted sum, 128 independent FMAs; fold groups; store.
// Lane (g=lane>>4, j=lane&15) covers concat-cols [j*16, j*16+16) of edge
// 4p+g in pass p.
// ---------------------------------------------------------------------------
__global__ __launch_bounds__(256) void attn_kernel(
    const unsigned short* __restrict__ ph, const int* __restrict__ ef,
    const unsigned short* __restrict__ wq_h, float* __restrict__ outp, int M)
{
    const int lane = threadIdx.x & 63;
    const int w    = threadIdx.x >> 6;
    const int n    = blockIdx.x * 4 + w;
    if (n >= M) return;

    const int g = lane >> 4;            // edge subgroup 0..3
    const int j = lane & 15;            // 16-col segment

    // wq segment for columns [j*16, j*16+16) (fp16, kept packed)
    const unsigned short* wp = wq_h + (size_t)n * TWO_D + j * 16;
    s8 wqa = *(const s8*)(wp);
    s8 wqb = *(const s8*)(wp + 8);

    int eidx = 0;
    if (lane < KNB) eidx = ef[n * KNB + lane];

    // ---- Phase 1: issue ALL 16 gather loads; pin them before compute ----
    s8 xa[8], xb[8];
#pragma unroll
    for (int p = 0; p < 8; ++p) {
        int e = __shfl(eidx, 4 * p + g, 64);
        const unsigned short* rp = ph + (size_t)e * TWO_D + j * 16;
        xa[p] = *(const s8*)(rp);
        xb[p] = *(const s8*)(rp + 8);
    }
    __builtin_amdgcn_sched_barrier(0);  // loads may not sink past this point

    // ---- Phase 2: partial dots (independent chains) ----
    float s[8];
#pragma unroll
    for (int p = 0; p < 8; ++p) {
        float t = dot8(xa[p], wqa, 0.f);
        s[p] = dot8(xb[p], wqb, t);
    }

    // ---- Phase 3: reduce trees (independent across p), group max, softmax --
#pragma unroll
    for (int p = 0; p < 8; ++p) {
#pragma unroll
        for (int off = 8; off; off >>= 1) s[p] += __shfl_xor(s[p], off, 64);
    }
    float m = -1e30f;
#pragma unroll
    for (int p = 0; p < 8; ++p) {
        float sb = __shfl_xor(s[p], 16, 64);   // partner group (xor 1 in g)
        float m2 = fmaxf(s[p], sb);
        float m3 = __shfl_xor(m2, 32, 64);     // partner pair (xor 2 in g)
        m = fmaxf(m, fmaxf(m2, m3));           // per-pass max over all 4 groups
    }
    float e[8];
    float psum = 0.f;
#pragma unroll
    for (int p = 0; p < 8; ++p) {
        e[p] = __expf(s[p] - m);
        psum += e[p];
    }
    // per-lane psum covers own group's 8 edges; fold the 4 groups
    psum += __shfl_xor(psum, 16, 64);
    psum += __shfl_xor(psum, 32, 64);

    // ---- Phase 4: weighted sum over own group's edges, then fold groups ----
    float o[16] = {};
#pragma unroll
    for (int p = 0; p < 8; ++p) {
        v16u ua, ub; ua.s = xa[p]; ub.s = xb[p];
#pragma unroll
        for (int t = 0; t < 4; ++t) {
            o[2*t]     = fmaf(e[p], (float)ua.h[t][0], o[2*t]);
            o[2*t+1]   = fmaf(e[p], (float)ua.h[t][1], o[2*t+1]);
            o[8+2*t]   = fmaf(e[p], (float)ub.h[t][0], o[8+2*t]);
            o[8+2*t+1] = fmaf(e[p], (float)ub.h[t][1], o[8+2*t+1]);
        }
    }
#pragma unroll
    for (int t = 0; t < 16; ++t) {
        o[t] += __shfl_xor(o[t], 16, 64);
        o[t] += __shfl_xor(o[t], 32, 64);
    }

    if (lane < 8) {                     // g==0, j<8: v-columns [lane*16, +16)
        float inv = 1.0f / psum;
        float* orow = outp + (size_t)n * D + lane * 16;
#pragma unroll
        for (int c = 0; c < 4; ++c) {
            float4 st = make_float4(o[4*c] * inv, o[4*c+1] * inv,
                                    o[4*c+2] * inv, o[4*c+3] * inv);
            *(float4*)(orow + 4 * c) = st;
        }
    }
}

// ---------------------------------------------------------------------------
extern "C" void kernel_launch(void* const* d_in, const int* in_sizes, int n_in,
                              void* d_out, int out_size, void* d_ws, size_t ws_size,
                              hipStream_t stream)
{
    const float* v_fea = (const float*)d_in[0];
    const float* t_emb = (const float*)d_in[1];
    const int*   ef    = (const int*)d_in[2];
    const float* W     = (const float*)d_in[3];
    float* outp = (float*)d_out;

    const int M = in_sizes[0] / D;                  // 50000
    // ws layout: wq_h (fp16, 25.6 MB) | ph (fp16 packed v|t, 25.6 MB)
    char* ws = (char*)d_ws;
    unsigned short* wq_h = (unsigned short*)ws;
    unsigned short* ph   = (unsigned short*)(ws + (size_t)M * TWO_D * 2);

    const int total = M * 16;
    cast_kernel<<<(total + 255) / 256, 256, 0, stream>>>(v_fea, t_emb, ph, total);

    dim3 gg((M + BM - 1) / BM, TWO_D / BN);
    gemm_wq_mfma<<<gg, 256, 0, stream>>>(ph, W, wq_h, M);
    attn_kernel<<<(M + 3) / 4, 256, 0, stream>>>(ph, ef, wq_h, outp, M);
}

// Round 3
// 224.979 us; speedup vs baseline: 1.0076x; 1.0076x over previous
//
#include <hip/hip_runtime.h>
#include <hip/hip_bf16.h>

// Problem constants: N=50000, K=32, D=128.
#define D     128
#define TWO_D 256
#define KNB   32

typedef __attribute__((ext_vector_type(8))) short    s8;   // 8 x 16-bit (4 VGPR)
typedef __attribute__((ext_vector_type(8))) _Float16 h8;   // mfma operand view
typedef __attribute__((ext_vector_type(2))) _Float16 h2v;
typedef __attribute__((ext_vector_type(4))) float    f4;   // MFMA acc

__device__ inline unsigned short f2h(float f) {
    return __builtin_bit_cast(unsigned short, (_Float16)f);
}
__device__ inline float h2f(unsigned short u) {
    return (float)__builtin_bit_cast(_Float16, u);
}

union v16u { s8 s; h2v h[4]; };

// 8-elem fp16 dot with f32 accumulate; v_dot2_f32_f16 when available.
__device__ inline float dot8(s8 x, s8 w, float acc) {
#if __has_builtin(__builtin_amdgcn_fdot2)
    v16u ux, uw; ux.s = x; uw.s = w;
#pragma unroll
    for (int j = 0; j < 4; ++j)
        acc = __builtin_amdgcn_fdot2(ux.h[j], uw.h[j], acc, false);
#else
#pragma unroll
    for (int j = 0; j < 8; ++j)
        acc = fmaf(h2f((unsigned short)x[j]), h2f((unsigned short)w[j]), acc);
#endif
    return acc;
}

// ---------------------------------------------------------------------------
// Cast kernel: v_fea, t_emb (f32) -> packed ph[n][0:128]=v, [128:256]=t (fp16).
// One contiguous 512B row per node => each edge gather is a single 512B block.
// ---------------------------------------------------------------------------
__global__ __launch_bounds__(256) void cast_kernel(
    const float* __restrict__ a, const float* __restrict__ b,
    unsigned short* __restrict__ ph, int total)   // total = M*16
{
    int i = blockIdx.x * 256 + threadIdx.x;
    if (i >= total) return;
    int n = i >> 4, j = i & 15;
    const float4* pv = (const float4*)(a + (size_t)n * D + j * 8);
    const float4* pt = (const float4*)(b + (size_t)n * D + j * 8);
    float4 v0 = pv[0], v1 = pv[1];
    float4 t0 = pt[0], t1 = pt[1];
    s8 qv, qt;
    qv[0]=(short)f2h(v0.x); qv[1]=(short)f2h(v0.y); qv[2]=(short)f2h(v0.z); qv[3]=(short)f2h(v0.w);
    qv[4]=(short)f2h(v1.x); qv[5]=(short)f2h(v1.y); qv[6]=(short)f2h(v1.z); qv[7]=(short)f2h(v1.w);
    qt[0]=(short)f2h(t0.x); qt[1]=(short)f2h(t0.y); qt[2]=(short)f2h(t0.z); qt[3]=(short)f2h(t0.w);
    qt[4]=(short)f2h(t1.x); qt[5]=(short)f2h(t1.y); qt[6]=(short)f2h(t1.z); qt[7]=(short)f2h(t1.w);
    *(s8*)(ph + (size_t)n * TWO_D + j * 8)     = qv;
    *(s8*)(ph + (size_t)n * TWO_D + D + j * 8) = qt;
}

// ---------------------------------------------------------------------------
// Kernel A: wq = ph @ W^T via fp16 MFMA. A-tiles read pre-cast packed fp16
// rows directly; only W (L2-resident) converted inline. wq stored fp16.
// 128x128 tile, BK=32, 4 waves; wave w: rows [w*32, w*32+32).
// ---------------------------------------------------------------------------
#define BM 128
#define BN 128
#define BK 32
#define LDT 56   // row stride (elems): 112 B = 16B-aligned; 2-way banks only

__global__ __launch_bounds__(256) void gemm_wq_mfma(
    const unsigned short* __restrict__ ph,
    const float* __restrict__ W, unsigned short* __restrict__ wq_h, int M)
{
    __shared__ unsigned short As[BM][LDT];
    __shared__ unsigned short Bs[BN][LDT];

    const int tid  = threadIdx.x;
    const int w    = tid >> 6;
    const int lane = tid & 63;
    const int quad = lane >> 4;
    const int l16  = lane & 15;
    const int row0 = blockIdx.x * BM;
    const int i0   = blockIdx.y * BN;

    f4 acc[2][8] = {};

    const int srow = tid >> 1;          // 0..127 (tile row this thread stages)
    const int seg  = tid & 1;           // 16-elem k-segment
    int ga = row0 + srow; if (ga >= M) ga = M - 1;   // clamp (stores guarded)

    for (int kt = 0; kt < TWO_D; kt += BK) {
        // A: packed fp16 source, direct copy. 32 B/thread.
        const unsigned short* pa = ph + (size_t)ga * TWO_D + kt + seg * 16;
        s8 a0 = *(const s8*)(pa);
        s8 a1 = *(const s8*)(pa + 8);
        // B: W f32 rows, inline cvt. 16 floats/thread.
        const float* pb = W + (size_t)(i0 + srow) * TWO_D + kt + seg * 16;
        float4 b0 = *(const float4*)(pb);
        float4 b1 = *(const float4*)(pb + 4);
        float4 b2 = *(const float4*)(pb + 8);
        float4 b3 = *(const float4*)(pb + 12);

        __syncthreads();   // prior iter's frag reads done before overwrite
        *(s8*)&As[srow][seg * 16]     = a0;
        *(s8*)&As[srow][seg * 16 + 8] = a1;
        {
            s8 q0, q1;
            q0[0]=(short)f2h(b0.x); q0[1]=(short)f2h(b0.y); q0[2]=(short)f2h(b0.z); q0[3]=(short)f2h(b0.w);
            q0[4]=(short)f2h(b1.x); q0[5]=(short)f2h(b1.y); q0[6]=(short)f2h(b1.z); q0[7]=(short)f2h(b1.w);
            q1[0]=(short)f2h(b2.x); q1[1]=(short)f2h(b2.y); q1[2]=(short)f2h(b2.z); q1[3]=(short)f2h(b2.w);
            q1[4]=(short)f2h(b3.x); q1[5]=(short)f2h(b3.y); q1[6]=(short)f2h(b3.z); q1[7]=(short)f2h(b3.w);
            *(s8*)&Bs[srow][seg * 16]     = q0;
            *(s8*)&Bs[srow][seg * 16 + 8] = q1;
        }
        __syncthreads();

        // A frag: m = lane&15 (+tile), k = quad*8+j; B frag: n = lane&15 (+tile).
        s8 af0 = *(const s8*)&As[w * 32 + l16][quad * 8];
        s8 af1 = *(const s8*)&As[w * 32 + 16 + l16][quad * 8];
#pragma unroll
        for (int nt = 0; nt < 8; ++nt) {
            s8 bf = *(const s8*)&Bs[nt * 16 + l16][quad * 8];
            acc[0][nt] = __builtin_amdgcn_mfma_f32_16x16x32_f16(
                __builtin_bit_cast(h8, af0), __builtin_bit_cast(h8, bf), acc[0][nt], 0, 0, 0);
            acc[1][nt] = __builtin_amdgcn_mfma_f32_16x16x32_f16(
                __builtin_bit_cast(h8, af1), __builtin_bit_cast(h8, bf), acc[1][nt], 0, 0, 0);
        }
    }

    // Epilogue: D layout col=lane&15, row=quad*4+r.
#pragma unroll
    for (int mt = 0; mt < 2; ++mt) {
#pragma unroll
        for (int nt = 0; nt < 8; ++nt) {
#pragma unroll
            for (int r = 0; r < 4; ++r) {
                int grow = row0 + w * 32 + mt * 16 + quad * 4 + r;
                if (grow < M)
                    wq_h[(size_t)grow * TWO_D + i0 + nt * 16 + l16] = f2h(acc[mt][nt][r]);
            }
        }
    }
}

// ---------------------------------------------------------------------------
// Kernel B: gather + score + softmax + weighted sum. One wave per row, 4
// rows/block, NO LDS.
// amdgpu_waves_per_eu(4,4): pins occupancy target to 4 waves/EU => 128-VGPR
// budget. Without this the backend's memory-bound heuristic targets 10
// waves/EU (48 VGPR) and either sinks (r0/r1) or spills (r2) the 16-deep
// gather pipeline. ~114 VGPR live here; must stay <= 128.
//   Phase 1: ALL 16 gather loads issued, pinned by sched_barrier(0).
//   Phase 2: 8 independent partial-dot chains.
//   Phase 3: 8 independent 16-lane shuffle trees; global max before any exp
//            => exact softmax, 8 exps/lane, no rescale branch.
//   Phase 4: weighted sum, 128 independent FMAs; fold groups; store.
// Lane (g=lane>>4, j=lane&15) covers concat-cols [j*16, j*16+16) of edge
// 4p+g in pass p.
// ---------------------------------------------------------------------------
__global__ __attribute__((amdgpu_waves_per_eu(4, 4))) __launch_bounds__(256)
void attn_kernel(
    const unsigned short* __restrict__ ph, const int* __restrict__ ef,
    const unsigned short* __restrict__ wq_h, float* __restrict__ outp, int M)
{
    const int lane = threadIdx.x & 63;
    const int w    = threadIdx.x >> 6;
    const int n    = blockIdx.x * 4 + w;
    if (n >= M) return;

    const int g = lane >> 4;            // edge subgroup 0..3
    const int j = lane & 15;            // 16-col segment

    // wq segment for columns [j*16, j*16+16) (fp16, kept packed)
    const unsigned short* wp = wq_h + (size_t)n * TWO_D + j * 16;
    s8 wqa = *(const s8*)(wp);
    s8 wqb = *(const s8*)(wp + 8);

    int eidx = 0;
    if (lane < KNB) eidx = ef[n * KNB + lane];

    // ---- Phase 1: issue ALL 16 gather loads; pin them before compute ----
    s8 xa[8], xb[8];
#pragma unroll
    for (int p = 0; p < 8; ++p) {
        int e = __shfl(eidx, 4 * p + g, 64);
        const unsigned short* rp = ph + (size_t)e * TWO_D + j * 16;
        xa[p] = *(const s8*)(rp);
        xb[p] = *(const s8*)(rp + 8);
    }
    __builtin_amdgcn_sched_barrier(0);  // loads may not sink past this point

    // ---- Phase 2: partial dots (independent chains) ----
    float s[8];
#pragma unroll
    for (int p = 0; p < 8; ++p) {
        float t = dot8(xa[p], wqa, 0.f);
        s[p] = dot8(xb[p], wqb, t);
    }

    // ---- Phase 3: reduce trees (independent across p), group max, softmax --
#pragma unroll
    for (int p = 0; p < 8; ++p) {
#pragma unroll
        for (int off = 8; off; off >>= 1) s[p] += __shfl_xor(s[p], off, 64);
    }
    float m = -1e30f;
#pragma unroll
    for (int p = 0; p < 8; ++p) {
        float sb = __shfl_xor(s[p], 16, 64);   // partner group (xor 1 in g)
        float m2 = fmaxf(s[p], sb);
        float m3 = __shfl_xor(m2, 32, 64);     // partner pair (xor 2 in g)
        m = fmaxf(m, fmaxf(m2, m3));           // per-pass max over all 4 groups
    }
    float e[8];
    float psum = 0.f;
#pragma unroll
    for (int p = 0; p < 8; ++p) {
        e[p] = __expf(s[p] - m);
        psum += e[p];
    }
    // per-lane psum covers own group's 8 edges; fold the 4 groups
    psum += __shfl_xor(psum, 16, 64);
    psum += __shfl_xor(psum, 32, 64);

    // ---- Phase 4: weighted sum over own group's edges, then fold groups ----
    float o[16] = {};
#pragma unroll
    for (int p = 0; p < 8; ++p) {
        v16u ua, ub; ua.s = xa[p]; ub.s = xb[p];
#pragma unroll
        for (int t = 0; t < 4; ++t) {
            o[2*t]     = fmaf(e[p], (float)ua.h[t][0], o[2*t]);
            o[2*t+1]   = fmaf(e[p], (float)ua.h[t][1], o[2*t+1]);
            o[8+2*t]   = fmaf(e[p], (float)ub.h[t][0], o[8+2*t]);
            o[8+2*t+1] = fmaf(e[p], (float)ub.h[t][1], o[8+2*t+1]);
        }
    }
#pragma unroll
    for (int t = 0; t < 16; ++t) {
        o[t] += __shfl_xor(o[t], 16, 64);
        o[t] += __shfl_xor(o[t], 32, 64);
    }

    if (lane < 8) {                     // g==0, j<8: v-columns [lane*16, +16)
        float inv = 1.0f / psum;
        float* orow = outp + (size_t)n * D + lane * 16;
#pragma unroll
        for (int c = 0; c < 4; ++c) {
            float4 st = make_float4(o[4*c] * inv, o[4*c+1] * inv,
                                    o[4*c+2] * inv, o[4*c+3] * inv);
            *(float4*)(orow + 4 * c) = st;
        }
    }
}

// ---------------------------------------------------------------------------
extern "C" void kernel_launch(void* const* d_in, const int* in_sizes, int n_in,
                              void* d_out, int out_size, void* d_ws, size_t ws_size,
                              hipStream_t stream)
{
    const float* v_fea = (const float*)d_in[0];
    const float* t_emb = (const float*)d_in[1];
    const int*   ef    = (const int*)d_in[2];
    const float* W     = (const float*)d_in[3];
    float* outp = (float*)d_out;

    const int M = in_sizes[0] / D;                  // 50000
    // ws layout: wq_h (fp16, 25.6 MB) | ph (fp16 packed v|t, 25.6 MB)
    char* ws = (char*)d_ws;
    unsigned short* wq_h = (unsigned short*)ws;
    unsigned short* ph   = (unsigned short*)(ws + (size_t)M * TWO_D * 2);

    const int total = M * 16;
    cast_kernel<<<(total + 255) / 256, 256, 0, stream>>>(v_fea, t_emb, ph, total);

    dim3 gg((M + BM - 1) / BM, TWO_D / BN);
    gemm_wq_mfma<<<gg, 256, 0, stream>>>(ph, W, wq_h, M);
    attn_kernel<<<(M + 3) / 4, 256, 0, stream>>>(ph, ef, wq_h, outp, M);
}